// Round 4
// baseline (213.703 us; speedup 1.0000x reference)
//
#include <hip/hip_runtime.h>

#define NUM_LAYERS 1000
#define DIM 10
#define CL 8              // layers folded per chain-thread (125 * 8 = 1000 exactly)
#define NCH 125           // chains
#define SLOT 111          // floats per LDS affine slot; >=110 (100 M + 10 bias)!
                          // 111 % 32 = 15 (odd) -> conflict-free lane strides
#define TILE_Q4 1280      // apply: 256 threads * 5 float4 = 512 rows per tile
#define APPLY_BLOCKS 1536 // 6 blocks/CU * 256 CUs

typedef float f32x4 __attribute__((ext_vector_type(4)));  // native vec for nontemporal builtin

// ---------------------------------------------------------------------------
// compose_all: ONE block folds all 1000 layers.
//  Phase 1: thread t (t<125) sequentially composes layers [8t, 8t+8) as a full
//           10x11 affine in REGISTERS, writes the partial col-major to LDS
//           slot t: slot[j*10+r] = M[r][j] (j<10), slot[100+r] = bias
//           (bias == "column 10", offset 10*10 aliases 100+r).
//  Phase 2: 7-level tree 125->63->32->16->8->4->2->1, column-parallel:
//           11 lanes per item, 23 items per 256-thread pass. Odd levels carry
//           the unpaired last item through by copy. Readout uses src after the
//           final swap, so level-count parity doesn't matter.
//  Result written ROW-major: aff[r*10+k] = M[r][k], aff[100+r] = c[r].
// ---------------------------------------------------------------------------
__global__ __launch_bounds__(256, 1) void compose_all(const float* __restrict__ Ws,
                                                      const float* __restrict__ bs,
                                                      float* __restrict__ aff) {
    __shared__ float A[NCH * SLOT];              // 125*111*4 = 55.5 KB
    __shared__ float B[((NCH + 1) / 2) * SLOT];  // 63*111*4  = 28.0 KB
    const int tid = threadIdx.x;

    // ---- phase 1: register chains ----
    if (tid < NCH) {
        const int t = tid;
        const float4* __restrict__ W4 = (const float4*)Ws + (size_t)t * CL * 25;

        float Rc[DIM][DIM];   // Rc[j][r] = M[r][j] (col-major running affine)
        float bv[DIM];

        {   // R = layer CL*t
            float m[100];
            #pragma unroll
            for (int i = 0; i < 25; ++i) {
                float4 v = W4[i];
                m[4*i+0] = v.x; m[4*i+1] = v.y; m[4*i+2] = v.z; m[4*i+3] = v.w;
            }
            #pragma unroll
            for (int j = 0; j < DIM; ++j)
                #pragma unroll
                for (int r = 0; r < DIM; ++r)
                    Rc[j][r] = m[r * 10 + j];
            #pragma unroll
            for (int r = 0; r < DIM; ++r)
                bv[r] = bs[(size_t)t * CL * 10 + r];
        }

        #pragma unroll
        for (int s = 1; s < CL; ++s) {      // R <- L_{CL*t+s} o R
            float m[100];
            #pragma unroll
            for (int i = 0; i < 25; ++i) {
                float4 v = W4[s * 25 + i];
                m[4*i+0] = v.x; m[4*i+1] = v.y; m[4*i+2] = v.z; m[4*i+3] = v.w;
            }
            #pragma unroll
            for (int j = 0; j < DIM; ++j) { // col_j <- M * col_j
                float tmp[DIM];
                #pragma unroll
                for (int r = 0; r < DIM; ++r) {
                    float acc = 0.f;
                    #pragma unroll
                    for (int k = 0; k < DIM; ++k)
                        acc += m[r * 10 + k] * Rc[j][k];
                    tmp[r] = acc;
                }
                #pragma unroll
                for (int r = 0; r < DIM; ++r) Rc[j][r] = tmp[r];
            }
            float tb[DIM];                   // bias <- M*bias + b_l
            #pragma unroll
            for (int r = 0; r < DIM; ++r) {
                float acc = bs[((size_t)t * CL + s) * 10 + r];
                #pragma unroll
                for (int k = 0; k < DIM; ++k)
                    acc += m[r * 10 + k] * bv[k];
                tb[r] = acc;
            }
            #pragma unroll
            for (int r = 0; r < DIM; ++r) bv[r] = tb[r];
        }

        // write partial col-major to LDS slot t (lane stride 111 -> no conflicts)
        #pragma unroll
        for (int j = 0; j < DIM; ++j)
            #pragma unroll
            for (int r = 0; r < DIM; ++r)
                A[t * SLOT + j * 10 + r] = Rc[j][r];
        #pragma unroll
        for (int r = 0; r < DIM; ++r)
            A[t * SLOT + 100 + r] = bv[r];
    }

    // ---- phase 2: column-parallel tree fold ----
    const float* src = A;
    float* dst = B;
    int n = NCH;
    while (n > 1) {
        int half = (n + 1) >> 1;
        __syncthreads();
        if (tid < 253) {                    // 23 item-groups x 11 column-lanes
            const int j = tid % 11;         // column (j==10 -> j*10 = 100 = bias)
            for (int d = tid / 11; d < half; d += 23) {
                const float* F = src + (size_t)(2 * d) * SLOT;
                float o[DIM];
                if (2 * d + 1 < n) {        // dst = G o F
                    const float* G = F + SLOT;
                    float colf[DIM];
                    #pragma unroll
                    for (int r = 0; r < DIM; ++r) colf[r] = F[j * 10 + r];
                    #pragma unroll
                    for (int r = 0; r < DIM; ++r) {
                        float acc = (j == DIM) ? G[100 + r] : 0.f;
                        #pragma unroll
                        for (int k = 0; k < DIM; ++k)
                            acc += G[k * 10 + r] * colf[k];
                        o[r] = acc;
                    }
                } else {                    // odd level: carry through
                    #pragma unroll
                    for (int r = 0; r < DIM; ++r) o[r] = F[j * 10 + r];
                }
                float* D = dst + (size_t)d * SLOT;
                #pragma unroll
                for (int r = 0; r < DIM; ++r) D[j * 10 + r] = o[r];
            }
        }
        n = half;
        float* t2 = dst; dst = (float*)src; src = t2;
    }
    __syncthreads();
    // result is in src (post-final-swap), col-major. Transpose M on write.
    if (tid < 110) {
        if (tid < 100) {
            int j = tid / DIM, r = tid % DIM;   // src[j*10+r] = M[r][j]
            aff[r * DIM + j] = src[tid];
        } else {
            aff[tid] = src[tid];                // bias
        }
    }
}

// ---------------------------------------------------------------------------
// apply: out = M x + c. Persistent grid-stride blocks, software-pipelined:
// tile i+1's global loads are ISSUED (into regs) before tile i's compute and
// stores, so HBM stays fed through the compute/store phases. All global
// traffic is lane-contiguous float4; LDS redistributes to 20 contiguous
// floats per thread (2 rows), conflict-free.
// ---------------------------------------------------------------------------
__global__ __launch_bounds__(256, 6) void apply_affine(const float* __restrict__ x,
                                                       const float* __restrict__ aff,
                                                       float* __restrict__ out,
                                                       int nq4, int ntiles) {
    __shared__ float4 lds4[TILE_Q4];
    __shared__ float s[112];
    const int tid = threadIdx.x;
    int tile = blockIdx.x;
    if (tile >= ntiles) return;

    if (tid < 112) s[tid] = (tid < 110) ? aff[tid] : 0.f;

    const float4* __restrict__ xin = (const float4*)x;
    f32x4* __restrict__ op = (f32x4*)out;

    float4 r0, r1, r2, r3, r4;
    int q0 = tile * TILE_Q4;
    {   // prolog: tile 0 loads -> regs
        int q;
        q = q0 + 0 * 256 + tid; if (q < nq4) r0 = xin[q];
        q = q0 + 1 * 256 + tid; if (q < nq4) r1 = xin[q];
        q = q0 + 2 * 256 + tid; if (q < nq4) r2 = xin[q];
        q = q0 + 3 * 256 + tid; if (q < nq4) r3 = xin[q];
        q = q0 + 4 * 256 + tid; if (q < nq4) r4 = xin[q];
    }
    __syncthreads();                       // s[] ready

    for (;;) {
        // stage current tile regs -> LDS
        lds4[0 * 256 + tid] = r0;
        lds4[1 * 256 + tid] = r1;
        lds4[2 * 256 + tid] = r2;
        lds4[3 * 256 + tid] = r3;
        lds4[4 * 256 + tid] = r4;
        __syncthreads();

        const int q0c = tile * TILE_Q4;
        const int nt = tile + gridDim.x;
        if (nt < ntiles) {                 // issue NEXT tile loads (no wait)
            q0 = nt * TILE_Q4;
            int q;
            q = q0 + 0 * 256 + tid; if (q < nq4) r0 = xin[q];
            q = q0 + 1 * 256 + tid; if (q < nq4) r1 = xin[q];
            q = q0 + 2 * 256 + tid; if (q < nq4) r2 = xin[q];
            q = q0 + 3 * 256 + tid; if (q < nq4) r3 = xin[q];
            q = q0 + 4 * 256 + tid; if (q < nq4) r4 = xin[q];
        }

        // compute tile i from LDS (thread owns rows {2t, 2t+1} of the tile)
        if (q0c + 5 * tid + 5 <= nq4) {
            float xv[20];
            #pragma unroll
            for (int i = 0; i < 5; ++i) {
                float4 v = lds4[5 * tid + i];
                xv[4*i+0] = v.x; xv[4*i+1] = v.y; xv[4*i+2] = v.z; xv[4*i+3] = v.w;
            }
            float o[20];
            #pragma unroll
            for (int rr = 0; rr < 2; ++rr)
                #pragma unroll
                for (int j = 0; j < DIM; ++j) {
                    float acc = s[100 + j];
                    #pragma unroll
                    for (int k = 0; k < DIM; ++k)
                        acc += s[j * DIM + k] * xv[rr * DIM + k];
                    o[rr * DIM + j] = acc;
                }
            #pragma unroll
            for (int i = 0; i < 5; ++i)
                lds4[5 * tid + i] = make_float4(o[4*i+0], o[4*i+1], o[4*i+2], o[4*i+3]);
        }
        __syncthreads();

        // store tile i (coalesced, nontemporal: out is never re-read)
        {
            const f32x4* l4 = (const f32x4*)lds4;
            int q;
            q = q0c + 0 * 256 + tid; if (q < nq4) __builtin_nontemporal_store(l4[0 * 256 + tid], &op[q]);
            q = q0c + 1 * 256 + tid; if (q < nq4) __builtin_nontemporal_store(l4[1 * 256 + tid], &op[q]);
            q = q0c + 2 * 256 + tid; if (q < nq4) __builtin_nontemporal_store(l4[2 * 256 + tid], &op[q]);
            q = q0c + 3 * 256 + tid; if (q < nq4) __builtin_nontemporal_store(l4[3 * 256 + tid], &op[q]);
            q = q0c + 4 * 256 + tid; if (q < nq4) __builtin_nontemporal_store(l4[4 * 256 + tid], &op[q]);
        }

        tile = nt;
        if (tile >= ntiles) break;
        __syncthreads();                   // LDS free for next stage
    }
}

extern "C" void kernel_launch(void* const* d_in, const int* in_sizes, int n_in,
                              void* d_out, int out_size, void* d_ws, size_t ws_size,
                              hipStream_t stream) {
    const float* x  = (const float*)d_in[0];   // [BATCH, 10]
    const float* Ws = (const float*)d_in[1];   // [1000, 10, 10]
    const float* bs = (const float*)d_in[2];   // [1000, 10]
    float* out = (float*)d_out;

    float* ws_aff = (float*)d_ws;              // 110 floats

    compose_all<<<1, 256, 0, stream>>>(Ws, bs, ws_aff);

    const int nq4 = in_sizes[0] / 4;           // in_sizes is in floats
    const int ntiles = (nq4 + TILE_Q4 - 1) / TILE_Q4;
    const int nblk = (ntiles < APPLY_BLOCKS) ? ntiles : APPLY_BLOCKS;
    apply_affine<<<nblk, 256, 0, stream>>>(x, ws_aff, out, nq4, ntiles);
}

// Round 5
// 164.439 us; speedup vs baseline: 1.2996x; 1.2996x over previous
//
#include <hip/hip_runtime.h>

#define NUM_LAYERS 1000
#define DIM 10
#define STRIDE 112           // floats per affine slot (10x11 = 110, padded to 112)
#define LPB 16               // layers per block in K1
#define NBLK 63              // ceil(1000/16)
#define WQ4 320              // float4 per wave in apply (64 lanes * 5)
#define TILE_Q4 1280         // float4 per block (4 waves)

// Affine stored col-major in a slot: slot[j*10 + r] = M[r][j] for j<10,
// slot[100 + r] = c[r]. Compose dst = g(f(.)): col_j(dst) = M_g * col_j(f)
// (+ c_g when j==10). Lane j (0..10) owns column j.
__device__ inline void compose_one(const float* __restrict__ src,
                                   float* __restrict__ dst,
                                   int c, int lane) {
    const float* F = src + (size_t)(2 * c) * STRIDE;
    const float* G = src + (size_t)(2 * c + 1) * STRIDE;
    float colf[DIM], o[DIM];
    #pragma unroll
    for (int r = 0; r < DIM; ++r) colf[r] = F[lane * DIM + r];
    #pragma unroll
    for (int r = 0; r < DIM; ++r) {
        float acc = (lane == DIM) ? G[100 + r] : 0.f;
        #pragma unroll
        for (int k = 0; k < DIM; ++k)
            acc += G[k * DIM + r] * colf[k];
        o[r] = acc;
    }
    float* D = dst + (size_t)c * STRIDE;
    #pragma unroll
    for (int r = 0; r < DIM; ++r) D[lane * DIM + r] = o[r];
}

// ---------------------------------------------------------------------------
// K1 (proven round-0): block b composes layers [b*16, b*16+16) via a 4-level
// LDS tree: 16 -> 8 -> 4 -> 2 -> 1. One wave per compose.
// ---------------------------------------------------------------------------
__global__ __launch_bounds__(1024) void compose16(const float* __restrict__ Ws,
                                                  const float* __restrict__ bs,
                                                  float* __restrict__ wsout) {
    __shared__ float A[LPB * STRIDE];
    __shared__ float B[(LPB / 2) * STRIDE];
    const int tid = threadIdx.x;
    const int blk = blockIdx.x;

    for (int e = tid; e < LPB * 100; e += 1024) {
        int ll = e / 100, rem = e % 100;      // rem = r*10 + k
        int r = rem / 10, k = rem % 10;
        int l = blk * LPB + ll;
        float v = (l < NUM_LAYERS) ? Ws[(size_t)l * 100 + rem]
                                   : (r == k ? 1.f : 0.f);
        A[ll * STRIDE + k * DIM + r] = v;
    }
    for (int e = tid; e < LPB * DIM; e += 1024) {
        int ll = e / DIM, r = e % DIM;
        int l = blk * LPB + ll;
        float v = (l < NUM_LAYERS) ? bs[(size_t)l * DIM + r] : 0.f;
        A[ll * STRIDE + 100 + r] = v;
    }

    const int wave = tid >> 6, lane = tid & 63;
    const float* src = A;
    float* dst = B;
    for (int n = LPB / 2; n >= 1; n >>= 1) {   // n = 8,4,2,1
        __syncthreads();
        if (wave < n && lane <= DIM) compose_one(src, dst, wave, lane);
        const float* t = dst; dst = (float*)src; src = t;
    }
    __syncthreads();
    if (tid < 110) wsout[(size_t)blk * STRIDE + tid] = A[tid];
}

// ---------------------------------------------------------------------------
// K2 (proven round-0): one block folds the 63 chunk affines (padded to 64)
// via a 6-level tree. Writes the final affine ROW-major:
// aff[r*10+k] = M[r][k], aff[100+r] = c[r].
// ---------------------------------------------------------------------------
__global__ __launch_bounds__(1024) void compose_tree64(const float* __restrict__ wsin,
                                                       float* __restrict__ aff) {
    __shared__ float A[64 * STRIDE];
    __shared__ float B[32 * STRIDE];
    const int tid = threadIdx.x;

    for (int e = tid; e < 64 * STRIDE; e += 1024) {
        int chunk = e / STRIDE, pos = e % STRIDE;
        float v;
        if (pos >= 110)        v = 0.f;
        else if (chunk < NBLK) v = wsin[(size_t)chunk * STRIDE + pos];
        else v = (pos < 100 && (pos / 10 == pos % 10)) ? 1.f : 0.f;  // identity
        A[e] = v;
    }

    const int wave = tid >> 6, lane = tid & 63;
    const float* src = A;
    float* dst = B;
    for (int n = 32; n >= 1; n >>= 1) {        // n = 32,16,8,4,2,1
        __syncthreads();
        if (lane <= DIM)
            for (int c = wave; c < n; c += 16)
                compose_one(src, dst, c, lane);
        const float* t = dst; dst = (float*)src; src = t;
    }
    __syncthreads();
    if (tid < 110) {
        if (tid < 100) {
            int j = tid / DIM, r = tid % DIM;  // A[j*10+r] = M[r][j]
            aff[r * DIM + j] = A[tid];
        } else {
            aff[tid] = A[tid];                 // bias (also pads 110..111 as-is)
        }
    }
}

// ---------------------------------------------------------------------------
// K3: out = M x + c. BARRIER-FREE: each wave owns a private 5 KB LDS region
// and redistributes coalesced<->row-contiguous purely intra-wave, ordered by
// inline `s_waitcnt lgkmcnt(0)` (+ "memory" clobber + sched_barrier, guide
// rule #18). No __syncthreads -> no vmcnt(0) block-wide drains -> waves
// stream independently like a copy kernel. Global traffic: 100% lane-
// contiguous float4. LDS read stride 80 B = 2 lanes/bank = conflict-free.
// ---------------------------------------------------------------------------
__global__ __launch_bounds__(256) void apply_affine(const float* __restrict__ x,
                                                    const float* __restrict__ aff,
                                                    float* __restrict__ out,
                                                    int nq4) {
    __shared__ float4 lds4[4][WQ4];
    __shared__ float4 s4[28];                  // 112 floats (110 used)
    const int tid  = threadIdx.x;
    const int w    = tid >> 6, lane = tid & 63;
    const float* __restrict__ s = (const float*)s4;

    // Each wave redundantly stages the affine (same values -> benign race,
    // and each wave's own lgkmcnt wait below covers its own copy).
    if (lane < 28) s4[lane] = ((const float4*)aff)[lane];

    const int q0 = blockIdx.x * TILE_Q4 + w * WQ4;   // this wave's float4 base
    const float4* __restrict__ xin = (const float4*)x + q0;
    float4* __restrict__ op = (float4*)out + q0;
    const int rem = nq4 - q0;                  // float4s this wave still owns

    // coalesced loads: lane l takes float4 (i*64 + l)
    float4 r0, r1, r2, r3, r4;
    if (0 * 64 + lane < rem) r0 = xin[0 * 64 + lane];
    if (1 * 64 + lane < rem) r1 = xin[1 * 64 + lane];
    if (2 * 64 + lane < rem) r2 = xin[2 * 64 + lane];
    if (3 * 64 + lane < rem) r3 = xin[3 * 64 + lane];
    if (4 * 64 + lane < rem) r4 = xin[4 * 64 + lane];

    lds4[w][0 * 64 + lane] = r0;
    lds4[w][1 * 64 + lane] = r1;
    lds4[w][2 * 64 + lane] = r2;
    lds4[w][3 * 64 + lane] = r3;
    lds4[w][4 * 64 + lane] = r4;

    // intra-wave fence: all ds_writes complete before cross-lane ds_reads
    asm volatile("s_waitcnt lgkmcnt(0)" ::: "memory");
    __builtin_amdgcn_sched_barrier(0);

    // thread reads its own 20 contiguous floats = rows {2T, 2T+1}
    float xv[20];
    #pragma unroll
    for (int i = 0; i < 5; ++i) {
        float4 v = lds4[w][5 * lane + i];
        xv[4*i+0] = v.x; xv[4*i+1] = v.y; xv[4*i+2] = v.z; xv[4*i+3] = v.w;
    }

    float o[20];
    #pragma unroll
    for (int rr = 0; rr < 2; ++rr)
        #pragma unroll
        for (int j = 0; j < DIM; ++j) {
            float acc = s[100 + j];
            #pragma unroll
            for (int k = 0; k < DIM; ++k)
                acc += s[j * DIM + k] * xv[rr * DIM + k];
            o[rr * DIM + j] = acc;
        }

    // write back to the SAME per-lane addresses (no cross-lane WAR)
    #pragma unroll
    for (int i = 0; i < 5; ++i)
        lds4[w][5 * lane + i] = make_float4(o[4*i+0], o[4*i+1], o[4*i+2], o[4*i+3]);

    asm volatile("s_waitcnt lgkmcnt(0)" ::: "memory");
    __builtin_amdgcn_sched_barrier(0);

    // coalesced stores
    {
        float4 t0 = lds4[w][0 * 64 + lane];
        float4 t1 = lds4[w][1 * 64 + lane];
        float4 t2 = lds4[w][2 * 64 + lane];
        float4 t3 = lds4[w][3 * 64 + lane];
        float4 t4 = lds4[w][4 * 64 + lane];
        if (0 * 64 + lane < rem) op[0 * 64 + lane] = t0;
        if (1 * 64 + lane < rem) op[1 * 64 + lane] = t1;
        if (2 * 64 + lane < rem) op[2 * 64 + lane] = t2;
        if (3 * 64 + lane < rem) op[3 * 64 + lane] = t3;
        if (4 * 64 + lane < rem) op[4 * 64 + lane] = t4;
    }
}

extern "C" void kernel_launch(void* const* d_in, const int* in_sizes, int n_in,
                              void* d_out, int out_size, void* d_ws, size_t ws_size,
                              hipStream_t stream) {
    const float* x  = (const float*)d_in[0];   // [BATCH, 10]
    const float* Ws = (const float*)d_in[1];   // [1000, 10, 10]
    const float* bs = (const float*)d_in[2];   // [1000, 10]
    float* out = (float*)d_out;

    float* ws_chunks = (float*)d_ws;                      // NBLK * STRIDE floats
    float* ws_aff    = ws_chunks + NBLK * STRIDE;         // 112 floats (16B aligned)

    compose16<<<NBLK, 1024, 0, stream>>>(Ws, bs, ws_chunks);
    compose_tree64<<<1, 1024, 0, stream>>>(ws_chunks, ws_aff);

    const int nq4 = in_sizes[0] / 4;                      // in_sizes is in floats
    const int blocks = (nq4 + TILE_Q4 - 1) / TILE_Q4;
    apply_affine<<<blocks, 256, 0, stream>>>(x, ws_aff, out, nq4);
}